// Round 1
// baseline (150.234 us; speedup 1.0000x reference)
//
#include <hip/hip_runtime.h>
#include <hip/hip_bf16.h>
#include <cstdint>

#define BATCH  8192
#define INDIM  1024   // K
#define OUTDIM 2048   // N

typedef float  f32x4  __attribute__((ext_vector_type(4)));
typedef __bf16 bf16x8 __attribute__((ext_vector_type(8)));
typedef unsigned short u16x4 __attribute__((ext_vector_type(4)));

__device__ __forceinline__ uint16_t f2b(float f) {
    __hip_bfloat16 h = __float2bfloat16(f);
    return __builtin_bit_cast(uint16_t, h);
}

// async global->LDS, 16B per lane. LDS dest must be wave-uniform base + lane*16.
__device__ __forceinline__ void async_copy16(const void* g, void* l) {
    __builtin_amdgcn_global_load_lds(
        (__attribute__((address_space(1))) void*)(g),
        (__attribute__((address_space(3))) void*)(l),
        16, 0, 0);
}

// ---------------- prep: x (fp32 [B][K]) -> x_bf16 + x_sq --------------------
__global__ __launch_bounds__(256) void prep_x(const float* __restrict__ x,
                                              uint16_t* __restrict__ xbf,
                                              float* __restrict__ xsq) {
    const int row = blockIdx.x;
    const int tid = threadIdx.x;
    const float4 v = ((const float4*)(x + (size_t)row * INDIM))[tid];
    float s = v.x * v.x + v.y * v.y + v.z * v.z + v.w * v.w;
    u16x4 o;
    o.x = f2b(v.x); o.y = f2b(v.y); o.z = f2b(v.z); o.w = f2b(v.w);
    ((u16x4*)(xbf + (size_t)row * INDIM))[tid] = o;
#pragma unroll
    for (int off = 32; off > 0; off >>= 1) s += __shfl_down(s, off);
    __shared__ float ws[4];
    if ((tid & 63) == 0) ws[tid >> 6] = s;
    __syncthreads();
    if (tid == 0) xsq[row] = ws[0] + ws[1] + ws[2] + ws[3];
}

// ------- prep: P (fp32 [K][O]) -> Pt_bf16 [O][K] + p_sq (atomic accum) ------
__global__ __launch_bounds__(256) void prep_p(const float* __restrict__ P,
                                              uint16_t* __restrict__ ptbf,
                                              float* __restrict__ psq) {
    __shared__ float tile[32][33];
    __shared__ float csum[32];
    const int tx = threadIdx.x;   // 0..31
    const int ty = threadIdx.y;   // 0..7
    const int o0 = blockIdx.x * 32;
    const int k0 = blockIdx.y * 32;
    if (ty == 0) csum[tx] = 0.f;
    __syncthreads();
    float part = 0.f;
#pragma unroll
    for (int r = 0; r < 4; ++r) {
        const int k = ty + r * 8;
        const float v = P[(size_t)(k0 + k) * OUTDIM + o0 + tx];
        tile[k][tx] = v;
        part += v * v;
    }
    atomicAdd(&csum[tx], part);
    __syncthreads();
#pragma unroll
    for (int r = 0; r < 4; ++r) {
        const int o = ty + r * 8;
        ptbf[(size_t)(o0 + o) * INDIM + k0 + tx] = f2b(tile[tx][o]);
    }
    if (ty == 0) atomicAdd(&psq[o0 + tx], csum[tx]);
}

// ---------------- main GEMM + epilogue --------------------------------------
// C[m][n] = 2 * sum_k A[m][k] * Bt[n][k] - xsq[m] - psq[n]
// Tile 128x128, BK=64. 256 threads = 4 waves (2x2), each wave 64x64 = 4x4
// frags of mfma_f32_16x16x32_bf16.
#define TM 128
#define TN 128
#define BK 64

__global__ __launch_bounds__(256) void gemm_ep(const uint16_t* __restrict__ xbf,
                                               const uint16_t* __restrict__ ptbf,
                                               const float* __restrict__ xsq,
                                               const float* __restrict__ psq,
                                               float* __restrict__ out) {
    __shared__ __align__(16) uint16_t As[TM * BK];
    __shared__ __align__(16) uint16_t Bs[TN * BK];

    const int tid  = threadIdx.x;
    const int m0   = blockIdx.x * TM;   // 64 blocks
    const int n0   = blockIdx.y * TN;   // 16 blocks
    const int wave = tid >> 6;
    const int lane = tid & 63;
    const int wm   = (wave >> 1) * 64;  // wave row offset in tile
    const int wn   = (wave & 1) * 64;   // wave col offset in tile
    const int lrow = lane & 15;
    const int quad = lane >> 4;

    f32x4 acc[4][4];
    const f32x4 zero = {0.f, 0.f, 0.f, 0.f};
#pragma unroll
    for (int i = 0; i < 4; ++i)
#pragma unroll
        for (int j = 0; j < 4; ++j) acc[i][j] = zero;

    for (int kb = 0; kb < INDIM; kb += BK) {
        // stage A (128x64) and B (128x64) bf16 tiles, 16B per lane per inst
#pragma unroll
        for (int t = 0; t < 4; ++t) {
            const int id = t * 256 + tid;       // 0..1023 chunk id
            const int r  = id >> 3;             // tile row
            const int c  = id & 7;              // 16B chunk within row
            async_copy16(xbf  + (size_t)(m0 + r) * INDIM + kb + c * 8, As + id * 8);
            async_copy16(ptbf + (size_t)(n0 + r) * INDIM + kb + c * 8, Bs + id * 8);
        }
        __syncthreads();

#pragma unroll
        for (int ks = 0; ks < 2; ++ks) {        // two K=32 steps
            bf16x8 a[4], b[4];
#pragma unroll
            for (int i = 0; i < 4; ++i)
                a[i] = *(const bf16x8*)(As + (wm + i * 16 + lrow) * BK + ks * 32 + quad * 8);
#pragma unroll
            for (int j = 0; j < 4; ++j)
                b[j] = *(const bf16x8*)(Bs + (wn + j * 16 + lrow) * BK + ks * 32 + quad * 8);
#pragma unroll
            for (int i = 0; i < 4; ++i)
#pragma unroll
                for (int j = 0; j < 4; ++j)
                    acc[i][j] = __builtin_amdgcn_mfma_f32_16x16x32_bf16(a[i], b[j], acc[i][j], 0, 0, 0);
        }
        __syncthreads();
    }

    // epilogue: C/D layout col = lane&15, row = quad*4 + reg
    const float* xsq_w = xsq + m0 + wm;
    const float* psq_w = psq + n0 + wn;
    float ps[4];
#pragma unroll
    for (int j = 0; j < 4; ++j) ps[j] = psq_w[j * 16 + lrow];
#pragma unroll
    for (int i = 0; i < 4; ++i) {
        float xs[4];
#pragma unroll
        for (int r = 0; r < 4; ++r) xs[r] = xsq_w[i * 16 + quad * 4 + r];
        float* orow = out + (size_t)(m0 + wm + i * 16 + quad * 4) * OUTDIM + n0 + wn + lrow;
#pragma unroll
        for (int r = 0; r < 4; ++r)
#pragma unroll
            for (int j = 0; j < 4; ++j)
                orow[(size_t)r * OUTDIM + j * 16] = 2.f * acc[i][j][r] - xs[r] - ps[j];
    }
}

// ---------------- fallback (only if workspace is too small) -----------------
__global__ void fallback_kernel(const float* __restrict__ x,
                                const float* __restrict__ P,
                                float* __restrict__ out) {
    const int o = blockIdx.x * blockDim.x + threadIdx.x;
    const int b = blockIdx.y;
    float cr = 0.f, xq = 0.f, pq = 0.f;
    for (int i = 0; i < INDIM; ++i) {
        const float xv = x[(size_t)b * INDIM + i];
        const float pv = P[(size_t)i * OUTDIM + o];
        cr += xv * pv; xq += xv * xv; pq += pv * pv;
    }
    out[(size_t)b * OUTDIM + o] = 2.f * cr - xq - pq;
}

extern "C" void kernel_launch(void* const* d_in, const int* in_sizes, int n_in,
                              void* d_out, int out_size, void* d_ws, size_t ws_size,
                              hipStream_t stream) {
    (void)in_sizes; (void)n_in; (void)out_size;
    const float* x = (const float*)d_in[0];
    const float* P = (const float*)d_in[1];
    float* out = (float*)d_out;

    const size_t xbf_bytes = (size_t)BATCH * INDIM * 2;    // 16 MB
    const size_t pt_bytes  = (size_t)OUTDIM * INDIM * 2;   // 4 MB
    const size_t xsq_bytes = (size_t)BATCH * 4;
    const size_t psq_bytes = (size_t)OUTDIM * 4;
    const size_t need = xbf_bytes + pt_bytes + xsq_bytes + psq_bytes;

    if (ws_size < need) {
        // insurance path: slow but correct, no workspace
        fallback_kernel<<<dim3(OUTDIM / 256, BATCH), 256, 0, stream>>>(x, P, out);
        return;
    }

    uint16_t* xbf  = (uint16_t*)d_ws;
    uint16_t* ptbf = (uint16_t*)((char*)d_ws + xbf_bytes);
    float*    xsq  = (float*)((char*)d_ws + xbf_bytes + pt_bytes);
    float*    psq  = xsq + BATCH;

    hipMemsetAsync(psq, 0, psq_bytes, stream);
    prep_x<<<BATCH, 256, 0, stream>>>(x, xbf, xsq);
    prep_p<<<dim3(OUTDIM / 32, INDIM / 32), dim3(32, 8), 0, stream>>>(P, ptbf, psq);
    gemm_ep<<<dim3(BATCH / TM, OUTDIM / TN), 256, 0, stream>>>(xbf, ptbf, xsq, psq, out);
}

// Round 2
// 138.128 us; speedup vs baseline: 1.0876x; 1.0876x over previous
//
#include <hip/hip_runtime.h>
#include <hip/hip_bf16.h>
#include <cstdint>

#define BATCH  8192
#define INDIM  1024   // K
#define OUTDIM 2048   // N

typedef float  f32x4  __attribute__((ext_vector_type(4)));
typedef __bf16 bf16x8 __attribute__((ext_vector_type(8)));
typedef unsigned short u16x4 __attribute__((ext_vector_type(4)));
typedef unsigned short u16x8 __attribute__((ext_vector_type(8)));

__device__ __forceinline__ uint16_t f2b(float f) {
    __hip_bfloat16 h = __float2bfloat16(f);
    return __builtin_bit_cast(uint16_t, h);
}

// async global->LDS, 16B per lane. LDS dest is wave-uniform base + lane*16.
__device__ __forceinline__ void async_copy16(const void* g, void* l) {
    __builtin_amdgcn_global_load_lds(
        (__attribute__((address_space(1))) void*)(g),
        (__attribute__((address_space(3))) void*)(l),
        16, 0, 0);
}

// ---------------- prep: x (fp32 [B][K]) -> x_bf16 + x_sq --------------------
// One wave per row, 4 rows per block. Also zeroes psq (this kernel completes
// before prep_p starts — stream ordering).
__global__ __launch_bounds__(256) void prep_x(const float* __restrict__ x,
                                              uint16_t* __restrict__ xbf,
                                              float* __restrict__ xsq,
                                              float* __restrict__ psq) {
    const int wave = threadIdx.x >> 6;
    const int lane = threadIdx.x & 63;
    const int row  = blockIdx.x * 4 + wave;
    const f32x4* src = (const f32x4*)(x + (size_t)row * INDIM);
    u16x4* dst = (u16x4*)(xbf + (size_t)row * INDIM);
    float s = 0.f;
#pragma unroll
    for (int w = 0; w < 4; ++w) {
        const f32x4 v = src[lane + w * 64];
        s += v.x * v.x + v.y * v.y + v.z * v.z + v.w * v.w;
        u16x4 o;
        o.x = f2b(v.x); o.y = f2b(v.y); o.z = f2b(v.z); o.w = f2b(v.w);
        dst[lane + w * 64] = o;
    }
#pragma unroll
    for (int off = 32; off > 0; off >>= 1) s += __shfl_down(s, off);
    if (lane == 0 && wave == 0) psq[blockIdx.x] = 0.f;  // grid == OUTDIM == 2048
    if (lane == 0) xsq[row] = s;
}

// ------- prep: P (fp32 [K][O]) -> Pt_bf16 [O][K] + p_sq (atomic accum) ------
// 64(k) x 32(o) tile; write phase emits 16B u16x8 stores (full coalescing).
__global__ __launch_bounds__(256) void prep_p(const float* __restrict__ P,
                                              uint16_t* __restrict__ ptbf,
                                              float* __restrict__ psq) {
    __shared__ float tile[64][33];
    __shared__ float csum[32];
    const int tx = threadIdx.x;   // 0..31 (o)
    const int ty = threadIdx.y;   // 0..7
    const int o0 = blockIdx.x * 32;
    const int k0 = blockIdx.y * 64;
    if (ty == 0) csum[tx] = 0.f;
    __syncthreads();
    float part = 0.f;
#pragma unroll
    for (int r = 0; r < 8; ++r) {
        const int k = ty + r * 8;
        const float v = P[(size_t)(k0 + k) * OUTDIM + o0 + tx];
        tile[k][tx] = v;
        part += v * v;
    }
    atomicAdd(&csum[tx], part);
    __syncthreads();
    const int tid = ty * 32 + tx;
    const int o   = tid >> 3;         // 0..31
    const int kc  = (tid & 7) * 8;    // 0..56
    u16x8 w;
#pragma unroll
    for (int j = 0; j < 8; ++j) w[j] = f2b(tile[kc + j][o]);
    *(u16x8*)(ptbf + (size_t)(o0 + o) * INDIM + k0 + kc) = w;
    if (ty == 0) atomicAdd(&psq[o0 + tx], csum[tx]);
}

// ---------------- main GEMM + epilogue --------------------------------------
// C[m][n] = 2 * sum_k A[m][k] * Bt[n][k] - xsq[m] - psq[n]
// Tile 128x128, BK=64, 4 waves (2x2), each wave 64x64 via 4x4 frags of
// mfma_f32_16x16x32_bf16. LDS chunks XOR-swizzled: slot (r,c) holds global
// chunk c ^ (r&7) so fragment reads spread uniformly over all bank groups.
#define TM 128
#define TN 128
#define BK 64

__global__ __launch_bounds__(256) void gemm_ep(const uint16_t* __restrict__ xbf,
                                               const uint16_t* __restrict__ ptbf,
                                               const float* __restrict__ xsq,
                                               const float* __restrict__ psq,
                                               float* __restrict__ out) {
    __shared__ __align__(16) uint16_t As[TM * BK];
    __shared__ __align__(16) uint16_t Bs[TN * BK];

    const int tid  = threadIdx.x;
    const int m0   = blockIdx.x * TM;   // 64 blocks
    const int n0   = blockIdx.y * TN;   // 16 blocks
    const int wave = tid >> 6;
    const int lane = tid & 63;
    const int wm   = (wave >> 1) * 64;
    const int wn   = (wave & 1) * 64;
    const int lrow = lane & 15;
    const int quad = lane >> 4;
    const int sw   = lrow & 7;          // read-side swizzle key

    f32x4 acc[4][4];
    const f32x4 zero = {0.f, 0.f, 0.f, 0.f};
#pragma unroll
    for (int i = 0; i < 4; ++i)
#pragma unroll
        for (int j = 0; j < 4; ++j) acc[i][j] = zero;

    for (int kb = 0; kb < INDIM; kb += BK) {
        // stage A (128x64) and B (128x64); lane sources the XOR'd chunk so
        // slot (r, cs) ends up holding chunk cs ^ (r&7)
#pragma unroll
        for (int t = 0; t < 4; ++t) {
            const int id = t * 256 + tid;       // slot id 0..1023
            const int r  = id >> 3;             // tile row
            const int cs = id & 7;              // slot chunk
            const int cg = cs ^ (r & 7);        // global chunk
            async_copy16(xbf  + (size_t)(m0 + r) * INDIM + kb + cg * 8, As + id * 8);
            async_copy16(ptbf + (size_t)(n0 + r) * INDIM + kb + cg * 8, Bs + id * 8);
        }
        __syncthreads();

#pragma unroll
        for (int ks = 0; ks < 2; ++ks) {        // two K=32 steps
            bf16x8 a[4], b[4];
            const int c = ks * 4 + quad;        // chunk wanted
#pragma unroll
            for (int i = 0; i < 4; ++i)
                a[i] = *(const bf16x8*)(As + (wm + i * 16 + lrow) * BK + (c ^ sw) * 8);
#pragma unroll
            for (int j = 0; j < 4; ++j)
                b[j] = *(const bf16x8*)(Bs + (wn + j * 16 + lrow) * BK + (c ^ sw) * 8);
#pragma unroll
            for (int i = 0; i < 4; ++i)
#pragma unroll
                for (int j = 0; j < 4; ++j)
                    acc[i][j] = __builtin_amdgcn_mfma_f32_16x16x32_bf16(a[i], b[j], acc[i][j], 0, 0, 0);
        }
        __syncthreads();
    }

    // epilogue: C/D layout col = lane&15, row = quad*4 + reg
    const float* xsq_w = xsq + m0 + wm;
    const float* psq_w = psq + n0 + wn;
    float ps[4];
#pragma unroll
    for (int j = 0; j < 4; ++j) ps[j] = psq_w[j * 16 + lrow];
#pragma unroll
    for (int i = 0; i < 4; ++i) {
        float xs[4];
#pragma unroll
        for (int r = 0; r < 4; ++r) xs[r] = xsq_w[i * 16 + quad * 4 + r];
        float* orow = out + (size_t)(m0 + wm + i * 16 + quad * 4) * OUTDIM + n0 + wn + lrow;
#pragma unroll
        for (int r = 0; r < 4; ++r)
#pragma unroll
            for (int j = 0; j < 4; ++j)
                orow[(size_t)r * OUTDIM + j * 16] = 2.f * acc[i][j][r] - xs[r] - ps[j];
    }
}

// ---------------- fallback (only if workspace is too small) -----------------
__global__ void fallback_kernel(const float* __restrict__ x,
                                const float* __restrict__ P,
                                float* __restrict__ out) {
    const int o = blockIdx.x * blockDim.x + threadIdx.x;
    const int b = blockIdx.y;
    float cr = 0.f, xq = 0.f, pq = 0.f;
    for (int i = 0; i < INDIM; ++i) {
        const float xv = x[(size_t)b * INDIM + i];
        const float pv = P[(size_t)i * OUTDIM + o];
        cr += xv * pv; xq += xv * xv; pq += pv * pv;
    }
    out[(size_t)b * OUTDIM + o] = 2.f * cr - xq - pq;
}

extern "C" void kernel_launch(void* const* d_in, const int* in_sizes, int n_in,
                              void* d_out, int out_size, void* d_ws, size_t ws_size,
                              hipStream_t stream) {
    (void)in_sizes; (void)n_in; (void)out_size;
    const float* x = (const float*)d_in[0];
    const float* P = (const float*)d_in[1];
    float* out = (float*)d_out;

    const size_t xbf_bytes = (size_t)BATCH * INDIM * 2;    // 16 MB
    const size_t pt_bytes  = (size_t)OUTDIM * INDIM * 2;   // 4 MB
    const size_t xsq_bytes = (size_t)BATCH * 4;
    const size_t psq_bytes = (size_t)OUTDIM * 4;
    const size_t need = xbf_bytes + pt_bytes + xsq_bytes + psq_bytes;

    if (ws_size < need) {
        fallback_kernel<<<dim3(OUTDIM / 256, BATCH), 256, 0, stream>>>(x, P, out);
        return;
    }

    uint16_t* xbf  = (uint16_t*)d_ws;
    uint16_t* ptbf = (uint16_t*)((char*)d_ws + xbf_bytes);
    float*    xsq  = (float*)((char*)d_ws + xbf_bytes + pt_bytes);
    float*    psq  = xsq + BATCH;

    prep_x<<<BATCH / 4, 256, 0, stream>>>(x, xbf, xsq, psq);
    prep_p<<<dim3(OUTDIM / 32, INDIM / 64), dim3(32, 8), 0, stream>>>(P, ptbf, psq);
    gemm_ep<<<dim3(BATCH / TM, OUTDIM / TN), 256, 0, stream>>>(xbf, ptbf, xsq, psq, out);
}